// Round 3
// baseline (1114.672 us; speedup 1.0000x reference)
//
#include <hip/hip_runtime.h>
#include <math.h>

#define BB 4
#define SS 2048
#define NH 8
#define HD 64
#define HID 512
#define EPSV 1e-5f

#define NROWS (BB * SS)                // 8192 (b,s) rows
#define QKV_ELEMS (BB * NH * SS * HD)  // 4,194,304
#define TOTROWS (BB * NH * SS)         // 65536 (b,h,s) rows
#define NJT (SS / 128)                 // 16 j-tiles

typedef __attribute__((ext_vector_type(8))) short short8;
typedef __attribute__((ext_vector_type(4))) float f32x4;

__device__ __forceinline__ unsigned short f2bf(float f) {
  unsigned u = __builtin_bit_cast(unsigned, f);
  u += 0x7fff + ((u >> 16) & 1);  // RNE
  return (unsigned short)(u >> 16);
}

// ---------------------------------------------------------------------------
// bf16-MFMA GEMM: C = A(M x 512) @ W(512 x 512)^T + bias.
// 128x128 tile, 256 threads (4 waves, 2x2 quadrants of 64x64), K-step 32.
// A and W converted f32->bf16 during LDS staging; fp32 MFMA accumulate.
// MODE 0: C f32 [m][n].  MODE 1: C f32 split-head [b,h,s,d].
// MODE 2: C bf16 transposed per head [bh][d][s] (for V -> PV B-operand).
// ---------------------------------------------------------------------------
template <int MODE>
__global__ __launch_bounds__(256, 2) void gemm_bf16(const float* __restrict__ A,
                                                    const float* __restrict__ W,
                                                    const float* __restrict__ bias,
                                                    void* __restrict__ Cout) {
  __shared__ unsigned short As[128][40];  // 32 k + 8 pad (80 B rows)
  __shared__ unsigned short Ws[128][40];
  const int m0 = blockIdx.y * 128;
  const int n0 = blockIdx.x * 128;
  const int tid = threadIdx.x;
  const int lane = tid & 63;
  const int w = tid >> 6;
  const int wr = w >> 1;  // wave row-half
  const int wc = w & 1;   // wave col-half
  const int l16 = lane & 15;
  const int lq = lane >> 4;  // 0..3

  f32x4 acc[4][4];
#pragma unroll
  for (int mr = 0; mr < 4; ++mr)
#pragma unroll
    for (int nc = 0; nc < 4; ++nc) acc[mr][nc] = (f32x4)0.f;

  for (int k0 = 0; k0 < HID; k0 += 32) {
    __syncthreads();
// stage: 128 rows x 32 cols f32 -> bf16 ; 1024 float4 per operand
#pragma unroll
    for (int p = 0; p < 4; ++p) {
      int idx = tid + p * 256;
      int row = idx >> 3;
      int c4 = (idx & 7) * 4;
      float4 av = *(const float4*)&A[(size_t)(m0 + row) * HID + k0 + c4];
      float4 wv = *(const float4*)&W[(size_t)(n0 + row) * HID + k0 + c4];
      ushort4 ab = {f2bf(av.x), f2bf(av.y), f2bf(av.z), f2bf(av.w)};
      ushort4 wb = {f2bf(wv.x), f2bf(wv.y), f2bf(wv.z), f2bf(wv.w)};
      *(ushort4*)&As[row][c4] = ab;
      *(ushort4*)&Ws[row][c4] = wb;
    }
    __syncthreads();
    const int kb = lq * 8;
    short8 a[4], b[4];
#pragma unroll
    for (int mr = 0; mr < 4; ++mr)
      a[mr] = *(const short8*)&As[wr * 64 + mr * 16 + l16][kb];
#pragma unroll
    for (int nc = 0; nc < 4; ++nc)
      b[nc] = *(const short8*)&Ws[wc * 64 + nc * 16 + l16][kb];
#pragma unroll
    for (int mr = 0; mr < 4; ++mr)
#pragma unroll
      for (int nc = 0; nc < 4; ++nc)
        acc[mr][nc] = __builtin_amdgcn_mfma_f32_16x16x32_bf16(a[mr], b[nc], acc[mr][nc], 0, 0, 0);
  }

// epilogue: D lane mapping col = lane&15, row = (lane>>4)*4 + jj
#pragma unroll
  for (int nc = 0; nc < 4; ++nc) {
    const int n = n0 + wc * 64 + nc * 16 + l16;
    const float bv = bias[n];
#pragma unroll
    for (int mr = 0; mr < 4; ++mr) {
#pragma unroll
      for (int jj = 0; jj < 4; ++jj) {
        const int m = m0 + wr * 64 + mr * 16 + lq * 4 + jj;
        float v = acc[mr][nc][jj] + bv;
        if (MODE == 0) {
          ((float*)Cout)[(size_t)m * HID + n] = v;
        } else if (MODE == 1) {
          const int b_ = m >> 11, s = m & (SS - 1);
          const int h = n >> 6, d = n & 63;
          ((float*)Cout)[(((size_t)(b_ * NH + h)) * SS + s) * HD + d] = v;
        } else {  // MODE 2: bf16 [bh][d][s]
          const int b_ = m >> 11, s = m & (SS - 1);
          const int h = n >> 6, d = n & 63;
          ((unsigned short*)Cout)[(((size_t)(b_ * NH + h)) * HD + d) * SS + s] = f2bf(v);
        }
      }
    }
  }
}

// ---------------------------------------------------------------------------
// Scores pass: 128-row i-tile per block, loop j-tiles of 128.
// 8x8 micro-tile per thread (rows ty+16r, cols tx+16c).
// Writes p' = exp(s - m_running) f32 into the attn region, msnap per
// (row, jtile), and final (m, sum) stats. Row max made tx-uniform via shfl.
// ---------------------------------------------------------------------------
__global__ __launch_bounds__(256, 2) void scores_kernel(
    const float* __restrict__ Q, const float* __restrict__ K,
    const int* __restrict__ mask, const float* __restrict__ temp,
    float* __restrict__ attn, float* __restrict__ stats,
    float* __restrict__ msnap) {
  __shared__ float Qs[128][68];
  __shared__ float Ks[128][68];
  __shared__ int Ms[128];

  const int bh = blockIdx.y;
  const int b = bh >> 3;
  const int h = bh & 7;
  const int i0 = blockIdx.x * 128;
  const int tid = threadIdx.x;
  const int ty = tid >> 4;  // 0..15
  const int tx = tid & 15;  // 0..15
  const float tmp = temp[h];

  const float* Qb = Q + (size_t)bh * SS * HD;
  const float* Kb = K + (size_t)bh * SS * HD;
  float* attn_b = attn + (size_t)bh * SS * SS;

// stage Q tile once: 128 x 64 f32 = 2048 float4
#pragma unroll
  for (int p = 0; p < 8; ++p) {
    int idx = tid + p * 256;
    int row = idx >> 4;
    int c4 = (idx & 15) * 4;
    *(float4*)&Qs[row][c4] = *(const float4*)&Qb[(size_t)(i0 + row) * HD + c4];
  }

  float m[8], sg[8];
#pragma unroll
  for (int r = 0; r < 8; ++r) {
    m[r] = -INFINITY;
    sg[r] = 0.f;
  }

  for (int j0 = 0; j0 < SS; j0 += 128) {
    __syncthreads();  // protect Ks reads from previous iter (also covers Qs staging)
#pragma unroll
    for (int p = 0; p < 8; ++p) {
      int idx = tid + p * 256;
      int row = idx >> 4;
      int c4 = (idx & 15) * 4;
      *(float4*)&Ks[row][c4] = *(const float4*)&Kb[(size_t)(j0 + row) * HD + c4];
    }
    if (tid < 128) Ms[tid] = mask[b * SS + j0 + tid];
    __syncthreads();

    float dist[8][8];
#pragma unroll
    for (int r = 0; r < 8; ++r)
#pragma unroll
      for (int c = 0; c < 8; ++c) dist[r][c] = 0.f;

#pragma unroll 2
    for (int d4 = 0; d4 < HD; d4 += 4) {
      float4 q4[8], k4[8];
#pragma unroll
      for (int r = 0; r < 8; ++r) q4[r] = *(const float4*)&Qs[ty + 16 * r][d4];
#pragma unroll
      for (int c = 0; c < 8; ++c) k4[c] = *(const float4*)&Ks[tx + 16 * c][d4];
#pragma unroll
      for (int r = 0; r < 8; ++r)
#pragma unroll
        for (int c = 0; c < 8; ++c) {
          dist[r][c] += fabsf(q4[r].x - k4[c].x);
          dist[r][c] += fabsf(q4[r].y - k4[c].y);
          dist[r][c] += fabsf(q4[r].z - k4[c].z);
          dist[r][c] += fabsf(q4[r].w - k4[c].w);
        }
    }

    const int jt = j0 >> 7;
#pragma unroll
    for (int r = 0; r < 8; ++r) {
      float s[8];
      float rmax = -INFINITY;
#pragma unroll
      for (int c = 0; c < 8; ++c) {
        float sc = -dist[r][c] * tmp;
        if (Ms[tx + 16 * c] == 0) sc = -1e9f;
        s[c] = sc;
        rmax = fmaxf(rmax, sc);
      }
// make row max uniform across the 16 tx lanes
#pragma unroll
      for (int off = 1; off < 16; off <<= 1) rmax = fmaxf(rmax, __shfl_xor(rmax, off));
      const float mnew = fmaxf(m[r], rmax);
      const int i = i0 + ty + 16 * r;
      float* arow = attn_b + (size_t)i * SS + j0;
      float psum = 0.f;
#pragma unroll
      for (int c = 0; c < 8; ++c) {
        float pv = __expf(s[c] - mnew);
        psum += pv;
        arow[tx + 16 * c] = pv;  // store p'
      }
      sg[r] = sg[r] * __expf(m[r] - mnew) + psum;
      m[r] = mnew;
      if (tx == 0) msnap[((size_t)bh * NJT + jt) * SS + i] = mnew;
    }
  }

// final stats: sum across the 16 tx lanes (m already uniform)
#pragma unroll
  for (int r = 0; r < 8; ++r) {
    float ssum = sg[r];
#pragma unroll
    for (int off = 1; off < 16; off <<= 1) ssum += __shfl_xor(ssum, off);
    if (tx == 0) {
      const int row = bh * SS + i0 + ty + 16 * r;
      stats[2 * row] = m[r];
      stats[2 * row + 1] = ssum;
    }
  }
}

// ---------------------------------------------------------------------------
// attn_pv: p = p' * exp(msnap - mfin) / sum ; rewrite attn f32 in place;
// PV via bf16 MFMA with pre-transposed V (Vt bf16 [bh][d][s]).
// Block: 128 i-rows x full 64 d; j-tiles of 128.
// ---------------------------------------------------------------------------
__global__ __launch_bounds__(256, 3) void attn_pv_kernel(
    const unsigned short* __restrict__ Vt, const float* __restrict__ stats,
    const float* __restrict__ msnap, float* __restrict__ attn,
    float* __restrict__ attn_out) {
  __shared__ unsigned short Ps[128][136];
  __shared__ unsigned short Vts[64][136];
  __shared__ float corr_s[128];

  const int bh = blockIdx.y;
  const int b = bh >> 3;
  const int h = bh & 7;
  const int i0 = blockIdx.x * 128;
  const int tid = threadIdx.x;
  const int lane = tid & 63;
  const int w = tid >> 6;
  const int wr = w >> 1;
  const int wc = w & 1;
  const int l16 = lane & 15;
  const int lq = lane >> 4;

  float* attn_b = attn + (size_t)bh * SS * SS;
  const unsigned short* Vtb = Vt + (size_t)bh * HD * SS;

  float mfin = 0.f, inv = 0.f;
  if (tid < 128) {
    const int row = bh * SS + i0 + tid;
    mfin = stats[2 * row];
    inv = 1.0f / stats[2 * row + 1];
  }

  f32x4 acc[4][2];
#pragma unroll
  for (int mr = 0; mr < 4; ++mr)
#pragma unroll
    for (int nc = 0; nc < 2; ++nc) acc[mr][nc] = (f32x4)0.f;

  for (int jt = 0; jt < NJT; ++jt) {
    const int j0 = jt * 128;
    __syncthreads();  // protect Ps/Vts/corr_s reuse
    if (tid < 128)
      corr_s[tid] = __expf(msnap[((size_t)bh * NJT + jt) * SS + i0 + tid] - mfin) * inv;
// stage Vt tile: 64 d-rows x 128 j-cols bf16 = 1024 short8 chunks
#pragma unroll
    for (int p = 0; p < 4; ++p) {
      int idx = tid + p * 256;
      int row = idx >> 4;        // 0..63  (FIXED: was idx>>3, overran Vts)
      int ch = (idx & 15) * 8;   // 0..120 (FIXED: was (idx&7)*8, half-staged)
      *(short8*)&Vts[row][ch] = *(const short8*)&Vtb[(size_t)row * SS + j0 + ch];
    }
    __syncthreads();
// p-phase: 128 x 128 f32 tile = 4096 float4
#pragma unroll
    for (int p = 0; p < 16; ++p) {
      int idx = tid + p * 256;
      int row = idx >> 5;
      int c4 = (idx & 31) * 4;
      float* ap = &attn_b[(size_t)(i0 + row) * SS + j0 + c4];
      float4 pv = *(float4*)ap;
      const float cr = corr_s[row];
      pv.x *= cr;
      pv.y *= cr;
      pv.z *= cr;
      pv.w *= cr;
      *(float4*)ap = pv;
      ushort4 pb = {f2bf(pv.x), f2bf(pv.y), f2bf(pv.z), f2bf(pv.w)};
      *(ushort4*)&Ps[row][c4] = pb;
    }
    __syncthreads();
// MFMA: out(128x64) += P(128x128) @ V(128x64)
#pragma unroll
    for (int ks = 0; ks < 4; ++ks) {
      const int kb = ks * 32 + lq * 8;
      short8 a[4], bf[2];
#pragma unroll
      for (int mr = 0; mr < 4; ++mr)
        a[mr] = *(const short8*)&Ps[wr * 64 + mr * 16 + l16][kb];
#pragma unroll
      for (int nc = 0; nc < 2; ++nc)
        bf[nc] = *(const short8*)&Vts[wc * 32 + nc * 16 + l16][kb];
#pragma unroll
      for (int mr = 0; mr < 4; ++mr)
#pragma unroll
        for (int nc = 0; nc < 2; ++nc)
          acc[mr][nc] = __builtin_amdgcn_mfma_f32_16x16x32_bf16(a[mr], bf[nc], acc[mr][nc], 0, 0, 0);
    }
  }

// epilogue: write [b, s, h*64 + d]
#pragma unroll
  for (int mr = 0; mr < 4; ++mr)
#pragma unroll
    for (int nc = 0; nc < 2; ++nc)
#pragma unroll
      for (int jj = 0; jj < 4; ++jj) {
        const int i = i0 + wr * 64 + mr * 16 + lq * 4 + jj;
        const int d = wc * 32 + nc * 16 + l16;
        attn_out[((size_t)(b * SS + i)) * HID + h * HD + d] = acc[mr][nc][jj];
      }
}

// ---------------------------------------------------------------------------
// Residual + LayerNorm
// ---------------------------------------------------------------------------
__global__ __launch_bounds__(256) void ln_kernel(const float* __restrict__ proj,
                                                 const float* __restrict__ query,
                                                 const float* __restrict__ gamma,
                                                 const float* __restrict__ beta,
                                                 float* __restrict__ out) {
  const int row = blockIdx.x;
  const int tid = threadIdx.x;

  float x[2];
  float sum = 0.f, sumsq = 0.f;
#pragma unroll
  for (int t = 0; t < 2; ++t) {
    const int c = tid + t * 256;
    float v = proj[(size_t)row * HID + c] + query[(size_t)row * HID + c];
    x[t] = v;
    sum += v;
    sumsq += v * v;
  }
#pragma unroll
  for (int off = 1; off < 64; off <<= 1) {
    sum += __shfl_xor(sum, off);
    sumsq += __shfl_xor(sumsq, off);
  }
  __shared__ float s1[4], s2[4];
  if ((tid & 63) == 0) {
    s1[tid >> 6] = sum;
    s2[tid >> 6] = sumsq;
  }
  __syncthreads();
  sum = s1[0] + s1[1] + s1[2] + s1[3];
  sumsq = s2[0] + s2[1] + s2[2] + s2[3];
  const float mu = sum * (1.f / HID);
  const float var = sumsq * (1.f / HID) - mu * mu;
  const float rstd = rsqrtf(var + EPSV);
#pragma unroll
  for (int t = 0; t < 2; ++t) {
    const int c = tid + t * 256;
    out[(size_t)row * HID + c] = (x[t] - mu) * rstd * gamma[c] + beta[c];
  }
}

// ---------------------------------------------------------------------------
extern "C" void kernel_launch(void* const* d_in, const int* in_sizes, int n_in,
                              void* d_out, int out_size, void* d_ws, size_t ws_size,
                              hipStream_t stream) {
  const float* query = (const float*)d_in[0];
  const float* key = (const float*)d_in[1];
  const float* value = (const float*)d_in[2];
  const int* mask = (const int*)d_in[3];
  const float* Wq = (const float*)d_in[4];
  const float* bq = (const float*)d_in[5];
  const float* Wk = (const float*)d_in[6];
  const float* bk = (const float*)d_in[7];
  const float* Wv = (const float*)d_in[8];
  const float* bv = (const float*)d_in[9];
  const float* Wo = (const float*)d_in[10];
  const float* bo = (const float*)d_in[11];
  const float* temp = (const float*)d_in[12];
  const float* gamma = (const float*)d_in[13];
  const float* beta = (const float*)d_in[14];

  float* out_final = (float*)d_out;                     // (B,S,HID)
  float* attn = (float*)d_out + (size_t)BB * SS * HID;  // (B,H,S,S)

  float* Qb = (float*)d_ws;                               // f32 [bh][s][d]
  float* Kb = Qb + QKV_ELEMS;                             // f32 [bh][s][d]
  unsigned short* Vt = (unsigned short*)(Kb + QKV_ELEMS); // bf16 [bh][d][s]
  float* stats = (float*)(Vt + QKV_ELEMS);                // 2 * TOTROWS
  float* msnap = stats + 2 * TOTROWS;                     // NJT * TOTROWS
  float* attn_out = Qb;  // reuse after scores pass
  float* proj = Kb;      // reuse after scores pass

  const dim3 blk(256);
  const dim3 ggrid(HID / 128, NROWS / 128);  // 4 x 64

  gemm_bf16<1><<<ggrid, blk, 0, stream>>>(query, Wq, bq, Qb);
  gemm_bf16<1><<<ggrid, blk, 0, stream>>>(key, Wk, bk, Kb);
  gemm_bf16<2><<<ggrid, blk, 0, stream>>>(value, Wv, bv, Vt);

  const dim3 sgrid(SS / 128, BB * NH);  // 16 x 32
  scores_kernel<<<sgrid, blk, 0, stream>>>(Qb, Kb, mask, temp, attn, stats, msnap);
  attn_pv_kernel<<<sgrid, blk, 0, stream>>>(Vt, stats, msnap, attn, attn_out);

  gemm_bf16<0><<<ggrid, blk, 0, stream>>>(attn_out, Wo, bo, proj);
  ln_kernel<<<NROWS, blk, 0, stream>>>(proj, query, gamma, beta, out_final);
}